// Round 7
// baseline (405.903 us; speedup 1.0000x reference)
//
#include <hip/hip_runtime.h>
#include <math.h>

#define U 128
#define GAMMA 28
#define TB 16        // batch rows per block (one MFMA tile N-dim)
#define NT 512       // 8 waves
#define HSTR 136     // halves per hA row: 128 + 8 pad (272 B, 16B-aligned)
#define ESTR 260     // floats per wfin row: 258 -> 260 (1040 B, 16B-aligned)

typedef _Float16 half8 __attribute__((ext_vector_type(8)));
typedef _Float16 half4 __attribute__((ext_vector_type(4)));
typedef float floatx4 __attribute__((ext_vector_type(4)));

__device__ __forceinline__ float rcp_f(float x) { return __builtin_amdgcn_rcpf(x); }
__device__ __forceinline__ float softplus_f(float x) {
    return fmaxf(x, 0.0f) + __logf(1.0f + __expf(-fabsf(x)));
}

// Eigen-style 13/6 minimax rational tanh, HORNER form (register-frugal:
// ~4 live temps vs Estrin's ~8 -> fits the 64-VGPR budget; R6's Estrin
// version spilled Rb to scratch: FETCH 244MB). |err|~1e-6 on [-7.905,7.905].
__device__ __forceinline__ float tanh_r(float x) {
    const float A1  = 4.89352455891786e-03f;
    const float A3  = 6.37261928875436e-04f;
    const float A5  = 1.48572235717979e-05f;
    const float A7  = 5.12229709037114e-08f;
    const float A9  = -8.60467152213735e-11f;
    const float A11 = 2.00018790482477e-13f;
    const float A13 = -2.76076847742355e-16f;
    const float B0  = 4.89352518554385e-03f;
    const float B2  = 2.26843463243900e-03f;
    const float B4  = 1.18534705686654e-04f;
    const float B6  = 1.19825839466702e-06f;
    const float t  = fminf(fmaxf(x, -7.90531110763549805f), 7.90531110763549805f);
    const float t2 = t * t;
    float np = fmaf(t2, A13, A11);
    np = fmaf(t2, np, A9);
    np = fmaf(t2, np, A7);
    np = fmaf(t2, np, A5);
    np = fmaf(t2, np, A3);
    np = fmaf(t2, np, A1);
    float dp = fmaf(t2, B6, B4);
    dp = fmaf(t2, dp, B2);
    dp = fmaf(t2, dp, B0);
    return (t * np) * rcp_f(dp);
}

__global__ __launch_bounds__(NT, 4) void fib_rnn_kernel(
    const float* __restrict__ inp,      // (B,49,1)
    const float* __restrict__ Kw,       // (1,384)
    const float* __restrict__ Rw,       // (128,384)
    const float* __restrict__ bias,     // (2,384)
    const float* __restrict__ dv_loc,   // (258)
    const float* __restrict__ dv_rho,   // (258)
    const float* __restrict__ dv_eps,   // (28,258)
    const float* __restrict__ samp,     // (27,B,1)
    float* __restrict__ out,            // (B,28,2)
    int B)
{
    __shared__ __align__(16) _Float16 hA[2][TB * HSTR];
    __shared__ __align__(16) float wfin[GAMMA * ESTR];   // per-step dense weights [s][2j+n]
    __shared__ float in_lds[TB * 49];
    __shared__ float samp_lds[27 * TB];
    __shared__ __align__(16) float wsum[2][8][TB][2];    // [parity][wave][row][n]
    __shared__ float epsB[GAMMA][2];
    __shared__ __align__(16) float out_lds[TB * GAMMA * 2];

    const int tid  = threadIdx.x;
    const int wv   = tid >> 6;          // wave 0..7
    const int lane = tid & 63;
    const int q    = lane >> 4;         // quad 0..3
    const int m16  = lane & 15;         // this lane's batch row
    const int j0   = wv * 16 + q * 4;   // first of this lane's 4 gate columns
    const int b0   = blockIdx.x * TB;

    const float Cc = 0.5413248546f;     // log(expm1(1))

    // ---- one-time staging
    for (int i = tid; i < TB * 48; i += NT) {
        int bl = i / 48, tt = i - bl * 48;
        in_lds[bl * 49 + tt] = inp[(size_t)(b0 + bl) * 49 + tt];
    }
    for (int i = tid; i < 2 * TB * HSTR; i += NT) (&hA[0][0])[i] = (_Float16)0.f;
    for (int i = tid; i < GAMMA * 258; i += NT) {
        int s = i / 258, t = i - 258 * s;
        float v = dv_eps[i];
        if (t < 256) {
            float sc = 1e-5f + 0.02f * softplus_f(Cc + dv_rho[t]);
            wfin[s * ESTR + t] = fmaf(sc, v, dv_loc[t]);
        } else {
            epsB[s][t - 256] = v;
        }
    }
    for (int i = tid; i < 27 * TB; i += NT) {
        int s = i >> 4, bl = i & 15;
        samp_lds[i] = samp[(size_t)s * B + b0 + bl];
    }

    // ---- stationary R^T fragments (A operand, fp16), PRE-SCALED:
    // z,r tiles by 0.5 (sigmoid(a)=0.5+0.5*tanh(a/2)); hh tile natural scale.
    half8 Rb[3][4];
    {
        const int   tiles[3] = {wv, wv + 8, wv + 16};
        const float tsc[3]   = {0.5f, 0.5f, 1.0f};
        #pragma unroll
        for (int t = 0; t < 3; ++t) {
            const int c = tiles[t] * 16 + m16;
            #pragma unroll
            for (int kt = 0; kt < 4; ++kt) {
                #pragma unroll
                for (int e = 0; e < 8; ++e)
                    Rb[t][kt][e] = (_Float16)(tsc[t] * Rw[(size_t)(kt * 32 + q * 8 + e) * 384 + c]);
            }
        }
    }

    // per-lane gate constants for columns j0..j0+3 (same scaling as Rb)
    float KzS[4], KrS[4], KhS[4], bzS[4], brS[4], bhxS[4], bhhS[4];
    #pragma unroll
    for (int i = 0; i < 4; ++i) {
        const int j = j0 + i;
        KzS[i]  = 0.5f * Kw[j];
        KrS[i]  = 0.5f * Kw[j + U];
        KhS[i]  = Kw[j + 2 * U];
        bzS[i]  = 0.5f * (bias[j] + bias[384 + j]);
        brS[i]  = 0.5f * (bias[j + U] + bias[384 + j + U]);
        bhxS[i] = bias[j + 2 * U];           // outside r-mult
        bhhS[i] = bias[384 + j + 2 * U];     // inside  r-mult -> acc2 init
    }
    const float wbl0 = dv_loc[256], wbl1 = dv_loc[257];
    const float wbs0 = 1e-5f + 0.02f * softplus_f(Cc + dv_rho[256]);
    const float wbs1 = 1e-5f + 0.02f * softplus_f(Cc + dv_rho[257]);

    float hprev[4] = {0.f, 0.f, 0.f, 0.f};

    __syncthreads();

    // ---- helpers
    auto mfma3 = [&](const int cu, floatx4& a0, floatx4& a1, floatx4& a2) {
        #pragma unroll
        for (int kt = 0; kt < 4; ++kt) {
            const half8 Bh = *reinterpret_cast<const half8*>(&hA[cu][m16 * HSTR + kt * 32 + q * 8]);
            a0 = __builtin_amdgcn_mfma_f32_16x16x32_f16(Rb[0][kt], Bh, a0, 0, 0, 0);
            a1 = __builtin_amdgcn_mfma_f32_16x16x32_f16(Rb[1][kt], Bh, a1, 0, 0, 0);
            a2 = __builtin_amdgcn_mfma_f32_16x16x32_f16(Rb[2][kt], Bh, a2, 0, 0, 0);
        }
    };
    auto hstore = [&](const int cu, const float hn[4]) {
        half4 hp;
        #pragma unroll
        for (int i = 0; i < 4; ++i) hp[i] = (_Float16)hn[i];
        *reinterpret_cast<half4*>(&hA[cu ^ 1][m16 * HSTR + j0]) = hp;
    };
    // gates: z = 0.5 + 0.5*tanh(a/2) (a/2 from pre-scaled MFMA); hh = tanh(th).
    // ZERO exp2 in the hot loop; 3 rcp per column (same rcp count as R2 base).
    auto gates4 = [&](const floatx4& az, const floatx4& ar, const floatx4& a2,
                      const float x, float hn[4]) {
        #pragma unroll
        for (int i = 0; i < 4; ++i) {
            const float z  = fmaf(0.5f, tanh_r(az[i]), 0.5f);
            const float r  = fmaf(0.5f, tanh_r(ar[i]), 0.5f);
            const float th = fmaf(r, a2[i], fmaf(x, KhS[i], bhxS[i]));
            const float hh = tanh_r(th);
            hn[i] = fmaf(z, hprev[i] - hh, hh);
            hprev[i] = hn[i];
        }
    };
    auto dense_part = [&](const int s, const float hn[4]) {
        const float4 wa = *reinterpret_cast<const float4*>(&wfin[s * ESTR + 2 * j0]);
        const float4 wb = *reinterpret_cast<const float4*>(&wfin[s * ESTR + 2 * j0 + 4]);
        float pv0 = hn[0] * wa.x + hn[1] * wa.z + hn[2] * wb.x + hn[3] * wb.z;
        float pv1 = hn[0] * wa.y + hn[1] * wa.w + hn[2] * wb.y + hn[3] * wb.w;
        pv0 += __shfl_xor(pv0, 16, 64);  pv1 += __shfl_xor(pv1, 16, 64);
        pv0 += __shfl_xor(pv0, 32, 64);  pv1 += __shfl_xor(pv1, 32, 64);
        if (q == 0)
            *reinterpret_cast<float2*>(&wsum[s & 1][wv][m16][0]) = make_float2(pv0, pv1);
    };

    // ================= encoder steps 0..46 (x known ahead -> fold x@K + bias
    // into the MFMA C-init) ==================================================
    float xcur = in_lds[m16 * 49];
    #pragma unroll 2
    for (int step = 0; step < 47; ++step) {
        const int cu = step & 1;                         // constant-folds under unroll 2
        const float xnext = in_lds[m16 * 49 + step + 1]; // prefetch
        floatx4 a0, a1, a2;
        #pragma unroll
        for (int i = 0; i < 4; ++i) {
            a0[i] = fmaf(xcur, KzS[i], bzS[i]);
            a1[i] = fmaf(xcur, KrS[i], brS[i]);
            a2[i] = bhhS[i];
        }
        mfma3(cu, a0, a1, a2);
        float hn[4];
        gates4(a0, a1, a2, xcur, hn);
        hstore(cu, hn);
        xcur = xnext;
        __syncthreads();
    }

    // ================= step 47 (last encoder step; emits dense partials s=0)
    {
        floatx4 a0, a1, a2;
        #pragma unroll
        for (int i = 0; i < 4; ++i) {
            a0[i] = fmaf(xcur, KzS[i], bzS[i]);
            a1[i] = fmaf(xcur, KrS[i], brS[i]);
            a2[i] = bhhS[i];
        }
        mfma3(1, a0, a1, a2);
        float hn[4];
        gates4(a0, a1, a2, xcur, hn);
        hstore(1, hn);
        dense_part(0, hn);
        __syncthreads();
    }

    // ================= feedback steps 48..74 (y from phase A; biases in C-init,
    // x*K stays as one fma per gate so phase A overlaps the MFMA chain) ======
    #pragma unroll 2
    for (int step = 48; step < 75; ++step) {
        const int cu = step & 1;
        const int sp = step - 48;
        floatx4 a0, a1, a2;
        #pragma unroll
        for (int i = 0; i < 4; ++i) { a0[i] = bzS[i]; a1[i] = brS[i]; a2[i] = bhhS[i]; }
        mfma3(cu, a0, a1, a2);

        // phase A: finish previous step's dense_var; produce this lane's y
        float sx = 0.f, sy = 0.f;
        #pragma unroll
        for (int w = 0; w < 8; ++w) {
            const float2 f = *reinterpret_cast<const float2*>(&wsum[sp & 1][w][m16][0]);
            sx += f.x; sy += f.y;
        }
        const float x20 = sx + fmaf(wbs0, epsB[sp][0], wbl0);
        const float x21 = sy + fmaf(wbs1, epsB[sp][1], wbl1);
        const float sc  = 1e-5f + 0.05f * softplus_f(Cc + x21);
        if (wv == 0 && q == 0)
            *reinterpret_cast<float2*>(&out_lds[m16 * 56 + sp * 2]) = make_float2(x20, sc);
        const float yv = fmaf(sc, samp_lds[sp * 16 + m16], x20);

        floatx4 az, ar;
        #pragma unroll
        for (int i = 0; i < 4; ++i) {
            az[i] = fmaf(yv, KzS[i], a0[i]);
            ar[i] = fmaf(yv, KrS[i], a1[i]);
        }
        float hn[4];
        gates4(az, ar, a2, yv, hn);
        hstore(cu, hn);
        dense_part(sp + 1, hn);
        __syncthreads();
    }

    // ---- final output s = 27 (parity 1)
    if (wv == 0 && q == 0) {
        float sx = 0.f, sy = 0.f;
        #pragma unroll
        for (int w = 0; w < 8; ++w) {
            const float2 f = *reinterpret_cast<const float2*>(&wsum[1][w][m16][0]);
            sx += f.x; sy += f.y;
        }
        const float x20 = sx + fmaf(wbs0, epsB[27][0], wbl0);
        const float x21 = sy + fmaf(wbs1, epsB[27][1], wbl1);
        const float sc  = 1e-5f + 0.05f * softplus_f(Cc + x21);
        *reinterpret_cast<float2*>(&out_lds[m16 * 56 + 54]) = make_float2(x20, sc);
    }
    __syncthreads();

    // ---- coalesced output burst: 16 rows x 28 x 2 floats = 224 float4, contiguous
    if (tid < 224) {
        const float4 v = reinterpret_cast<const float4*>(out_lds)[tid];
        reinterpret_cast<float4*>(out + (size_t)b0 * 56)[tid] = v;
    }
}

extern "C" void kernel_launch(void* const* d_in, const int* in_sizes, int n_in,
                              void* d_out, int out_size, void* d_ws, size_t ws_size,
                              hipStream_t stream) {
    const float* inp    = (const float*)d_in[0];
    const float* Kw     = (const float*)d_in[1];
    const float* Rw     = (const float*)d_in[2];
    const float* bias   = (const float*)d_in[3];
    const float* dv_loc = (const float*)d_in[4];
    const float* dv_rho = (const float*)d_in[5];
    const float* dv_eps = (const float*)d_in[6];
    const float* samp   = (const float*)d_in[7];
    float* out = (float*)d_out;
    const int B = in_sizes[0] / 49;   // 8192
    dim3 grid(B / TB), block(NT);
    hipLaunchKernelGGL(fib_rnn_kernel, grid, block, 0, stream,
                       inp, Kw, Rw, bias, dv_loc, dv_rho, dv_eps, samp, out, B);
}

// Round 8
// 222.585 us; speedup vs baseline: 1.8236x; 1.8236x over previous
//
#include <hip/hip_runtime.h>
#include <math.h>

#define U 128
#define GAMMA 28
#define TB 16        // batch rows per block (one MFMA tile N-dim)
#define NT 256       // 4 waves; each wave owns 6 MFMA tiles (2 col-groups x 3 gates)
#define HSTR 136     // halves per hA row: 128 + 8 pad (272 B, 16B-aligned)
#define ESTR 260     // floats per wfin row: 258 -> 260 (1040 B, 16B-aligned)

typedef _Float16 half8 __attribute__((ext_vector_type(8)));
typedef _Float16 half4 __attribute__((ext_vector_type(4)));
typedef float floatx4 __attribute__((ext_vector_type(4)));

__device__ __forceinline__ float rcp_f(float x) { return __builtin_amdgcn_rcpf(x); }
__device__ __forceinline__ float softplus_f(float x) {
    return fmaxf(x, 0.0f) + __logf(1.0f + __expf(-fabsf(x)));
}

// Eigen-style 13/6 minimax rational tanh, Horner form. |err|~1e-6 on
// [-7.905,7.905], clamped outside. ZERO exp ops; 1 rcp + ~14 full-rate.
// At NT=256/__launch_bounds__(256,2) the register budget is 256/thread,
// so this no longer spills (R6/R7 lesson: at 128/thread it spilled).
__device__ __forceinline__ float tanh_r(float x) {
    const float A1  = 4.89352455891786e-03f;
    const float A3  = 6.37261928875436e-04f;
    const float A5  = 1.48572235717979e-05f;
    const float A7  = 5.12229709037114e-08f;
    const float A9  = -8.60467152213735e-11f;
    const float A11 = 2.00018790482477e-13f;
    const float A13 = -2.76076847742355e-16f;
    const float B0  = 4.89352518554385e-03f;
    const float B2  = 2.26843463243900e-03f;
    const float B4  = 1.18534705686654e-04f;
    const float B6  = 1.19825839466702e-06f;
    const float t  = fminf(fmaxf(x, -7.90531110763549805f), 7.90531110763549805f);
    const float t2 = t * t;
    float np = fmaf(t2, A13, A11);
    np = fmaf(t2, np, A9);
    np = fmaf(t2, np, A7);
    np = fmaf(t2, np, A5);
    np = fmaf(t2, np, A3);
    np = fmaf(t2, np, A1);
    float dp = fmaf(t2, B6, B4);
    dp = fmaf(t2, dp, B2);
    dp = fmaf(t2, dp, B0);
    return (t * np) * rcp_f(dp);
}

__global__ __launch_bounds__(NT, 2) void fib_rnn_kernel(
    const float* __restrict__ inp,      // (B,49,1)
    const float* __restrict__ Kw,       // (1,384)
    const float* __restrict__ Rw,       // (128,384)
    const float* __restrict__ bias,     // (2,384)
    const float* __restrict__ dv_loc,   // (258)
    const float* __restrict__ dv_rho,   // (258)
    const float* __restrict__ dv_eps,   // (28,258)
    const float* __restrict__ samp,     // (27,B,1)
    float* __restrict__ out,            // (B,28,2)
    int B)
{
    __shared__ __align__(16) _Float16 hA[2][TB * HSTR];
    __shared__ __align__(16) float wfin[GAMMA * ESTR];   // per-step dense weights [s][2j+n]
    __shared__ float in_lds[TB * 49];
    __shared__ float samp_lds[27 * TB];
    __shared__ __align__(16) float wsum[2][4][TB][2];    // [parity][wave][row][n]
    __shared__ float epsB[GAMMA][2];
    __shared__ __align__(16) float out_lds[TB * GAMMA * 2];

    const int tid  = threadIdx.x;
    const int wv   = tid >> 6;          // wave 0..3
    const int lane = tid & 63;
    const int q    = lane >> 4;         // quad 0..3
    const int m16  = lane & 15;         // this lane's batch row
    const int jq   = wv * 16 + q * 4;   // per-group column base (within 128)
    const int b0   = blockIdx.x * TB;

    const float Cc = 0.5413248546f;     // log(expm1(1))

    // ---- one-time staging
    for (int i = tid; i < TB * 48; i += NT) {
        int bl = i / 48, tt = i - bl * 48;
        in_lds[bl * 49 + tt] = inp[(size_t)(b0 + bl) * 49 + tt];
    }
    for (int i = tid; i < 2 * TB * HSTR; i += NT) (&hA[0][0])[i] = (_Float16)0.f;
    for (int i = tid; i < GAMMA * 258; i += NT) {
        int s = i / 258, t = i - 258 * s;
        float v = dv_eps[i];
        if (t < 256) {
            float sc = 1e-5f + 0.02f * softplus_f(Cc + dv_rho[t]);
            wfin[s * ESTR + t] = fmaf(sc, v, dv_loc[t]);
        } else {
            epsB[s][t - 256] = v;
        }
    }
    for (int i = tid; i < 27 * TB; i += NT) {
        int s = i >> 4, bl = i & 15;
        samp_lds[i] = samp[(size_t)s * B + b0 + bl];
    }

    // ---- stationary R^T fragments (A operand, fp16), PRE-SCALED:
    // z,r tiles by 0.5 (sigmoid(a)=0.5+0.5*tanh(a/2)); hh tile natural scale.
    // Wave wv owns tiles {gt*8 + 4*g + wv : g in 0..1, gt in 0..2}
    //  -> columns gt*128 + g*64 + wv*16 + m16.
    half8 Rb[2][3][4];
    {
        #pragma unroll
        for (int g = 0; g < 2; ++g) {
            #pragma unroll
            for (int gt = 0; gt < 3; ++gt) {
                const float sc = (gt < 2) ? 0.5f : 1.0f;
                const int c = gt * 128 + g * 64 + wv * 16 + m16;
                #pragma unroll
                for (int kt = 0; kt < 4; ++kt) {
                    #pragma unroll
                    for (int e = 0; e < 8; ++e)
                        Rb[g][gt][kt][e] =
                            (_Float16)(sc * Rw[(size_t)(kt * 32 + q * 8 + e) * 384 + c]);
                }
            }
        }
    }

    // per-lane gate constants for the 2 column groups x 4 columns
    float KzS[2][4], KrS[2][4], KhS[2][4], bzS[2][4], brS[2][4], bhxS[2][4], bhhS[2][4];
    #pragma unroll
    for (int g = 0; g < 2; ++g) {
        #pragma unroll
        for (int i = 0; i < 4; ++i) {
            const int j = g * 64 + jq + i;   // column within 128
            KzS[g][i]  = 0.5f * Kw[j];
            KrS[g][i]  = 0.5f * Kw[j + U];
            KhS[g][i]  = Kw[j + 2 * U];
            bzS[g][i]  = 0.5f * (bias[j] + bias[384 + j]);
            brS[g][i]  = 0.5f * (bias[j + U] + bias[384 + j + U]);
            bhxS[g][i] = bias[j + 2 * U];
            bhhS[g][i] = bias[384 + j + 2 * U];
        }
    }
    const float wbl0 = dv_loc[256], wbl1 = dv_loc[257];
    const float wbs0 = 1e-5f + 0.02f * softplus_f(Cc + dv_rho[256]);
    const float wbs1 = 1e-5f + 0.02f * softplus_f(Cc + dv_rho[257]);

    float hprev[2][4] = {{0.f,0.f,0.f,0.f},{0.f,0.f,0.f,0.f}};

    __syncthreads();

    // ---- helpers
    // 24 MFMAs/step: 6 independent accumulator chains; Bh read once per kt
    // and shared across all 6 (ds_read count halves vs the 8-wave layout).
    auto mfma6 = [&](const int cu, floatx4 (&a)[2][3]) {
        #pragma unroll
        for (int kt = 0; kt < 4; ++kt) {
            const half8 Bh = *reinterpret_cast<const half8*>(&hA[cu][m16 * HSTR + kt * 32 + q * 8]);
            #pragma unroll
            for (int g = 0; g < 2; ++g) {
                #pragma unroll
                for (int gt = 0; gt < 3; ++gt)
                    a[g][gt] = __builtin_amdgcn_mfma_f32_16x16x32_f16(Rb[g][gt][kt], Bh, a[g][gt], 0, 0, 0);
            }
        }
    };
    auto hstore = [&](const int cu, const int g, const float hn[4]) {
        half4 hp;
        #pragma unroll
        for (int i = 0; i < 4; ++i) hp[i] = (_Float16)hn[i];
        *reinterpret_cast<half4*>(&hA[cu ^ 1][m16 * HSTR + g * 64 + jq]) = hp;
    };
    // gates for one column group: z = 0.5 + 0.5*tanh(a/2), hh = tanh(th).
    // ZERO exp2; 3 rcp per column.
    auto gates4g = [&](const int g, const floatx4& az, const floatx4& ar, const floatx4& a2,
                       const float x, float hn[4]) {
        #pragma unroll
        for (int i = 0; i < 4; ++i) {
            const float z  = fmaf(0.5f, tanh_r(az[i]), 0.5f);
            const float r  = fmaf(0.5f, tanh_r(ar[i]), 0.5f);
            const float th = fmaf(r, a2[i], fmaf(x, KhS[g][i], bhxS[g][i]));
            const float hh = tanh_r(th);
            hn[i] = fmaf(z, hprev[g][i] - hh, hh);
            hprev[g][i] = hn[i];
        }
    };
    auto dense_part = [&](const int s, const float hn0[4], const float hn1[4]) {
        // group g columns j = g*64 + jq + i -> wfin offsets 2*j + n
        const float4 wa0 = *reinterpret_cast<const float4*>(&wfin[s * ESTR + 2 * jq]);
        const float4 wb0 = *reinterpret_cast<const float4*>(&wfin[s * ESTR + 2 * jq + 4]);
        const float4 wa1 = *reinterpret_cast<const float4*>(&wfin[s * ESTR + 128 + 2 * jq]);
        const float4 wb1 = *reinterpret_cast<const float4*>(&wfin[s * ESTR + 128 + 2 * jq + 4]);
        float pv0 = hn0[0] * wa0.x + hn0[1] * wa0.z + hn0[2] * wb0.x + hn0[3] * wb0.z
                  + hn1[0] * wa1.x + hn1[1] * wa1.z + hn1[2] * wb1.x + hn1[3] * wb1.z;
        float pv1 = hn0[0] * wa0.y + hn0[1] * wa0.w + hn0[2] * wb0.y + hn0[3] * wb0.w
                  + hn1[0] * wa1.y + hn1[1] * wa1.w + hn1[2] * wb1.y + hn1[3] * wb1.w;
        pv0 += __shfl_xor(pv0, 16, 64);  pv1 += __shfl_xor(pv1, 16, 64);
        pv0 += __shfl_xor(pv0, 32, 64);  pv1 += __shfl_xor(pv1, 32, 64);
        if (q == 0)
            *reinterpret_cast<float2*>(&wsum[s & 1][wv][m16][0]) = make_float2(pv0, pv1);
    };
    auto enc_step = [&](const int cu, const float x, float hn0[4], float hn1[4]) {
        floatx4 a[2][3];
        #pragma unroll
        for (int g = 0; g < 2; ++g) {
            #pragma unroll
            for (int i = 0; i < 4; ++i) {
                a[g][0][i] = fmaf(x, KzS[g][i], bzS[g][i]);
                a[g][1][i] = fmaf(x, KrS[g][i], brS[g][i]);
                a[g][2][i] = bhhS[g][i];
            }
        }
        mfma6(cu, a);
        gates4g(0, a[0][0], a[0][1], a[0][2], x, hn0);
        gates4g(1, a[1][0], a[1][1], a[1][2], x, hn1);
        hstore(cu, 0, hn0);
        hstore(cu, 1, hn1);
    };

    // ================= encoder steps 0..46
    float hn0[4], hn1[4];
    float xcur = in_lds[m16 * 49];
    #pragma unroll 2
    for (int step = 0; step < 47; ++step) {
        const int cu = step & 1;
        const float xnext = in_lds[m16 * 49 + step + 1];
        enc_step(cu, xcur, hn0, hn1);
        xcur = xnext;
        __syncthreads();
    }
    // ---- step 47 (last encoder step; emits dense partials s=0)
    {
        enc_step(1, xcur, hn0, hn1);
        dense_part(0, hn0, hn1);
        __syncthreads();
    }

    // ================= feedback steps 48..74
    #pragma unroll 2
    for (int step = 48; step < 75; ++step) {
        const int cu = step & 1;
        const int sp = step - 48;
        floatx4 a[2][3];
        #pragma unroll
        for (int g = 0; g < 2; ++g) {
            #pragma unroll
            for (int i = 0; i < 4; ++i) {
                a[g][0][i] = bzS[g][i];
                a[g][1][i] = brS[g][i];
                a[g][2][i] = bhhS[g][i];
            }
        }
        mfma6(cu, a);

        // phase A: finish previous step's dense_var; produce this lane's y
        float sx = 0.f, sy = 0.f;
        #pragma unroll
        for (int w = 0; w < 4; ++w) {
            const float2 f = *reinterpret_cast<const float2*>(&wsum[sp & 1][w][m16][0]);
            sx += f.x; sy += f.y;
        }
        const float x20 = sx + fmaf(wbs0, epsB[sp][0], wbl0);
        const float x21 = sy + fmaf(wbs1, epsB[sp][1], wbl1);
        const float sc  = 1e-5f + 0.05f * softplus_f(Cc + x21);
        if (wv == 0 && q == 0)
            *reinterpret_cast<float2*>(&out_lds[m16 * 56 + sp * 2]) = make_float2(x20, sc);
        const float yv = fmaf(sc, samp_lds[sp * 16 + m16], x20);

        floatx4 az0, ar0, az1, ar1;
        #pragma unroll
        for (int i = 0; i < 4; ++i) {
            az0[i] = fmaf(yv, KzS[0][i], a[0][0][i]);
            ar0[i] = fmaf(yv, KrS[0][i], a[0][1][i]);
            az1[i] = fmaf(yv, KzS[1][i], a[1][0][i]);
            ar1[i] = fmaf(yv, KrS[1][i], a[1][1][i]);
        }
        gates4g(0, az0, ar0, a[0][2], yv, hn0);
        gates4g(1, az1, ar1, a[1][2], yv, hn1);
        hstore(cu, 0, hn0);
        hstore(cu, 1, hn1);
        dense_part(sp + 1, hn0, hn1);
        __syncthreads();
    }

    // ---- final output s = 27 (parity 1)
    if (wv == 0 && q == 0) {
        float sx = 0.f, sy = 0.f;
        #pragma unroll
        for (int w = 0; w < 4; ++w) {
            const float2 f = *reinterpret_cast<const float2*>(&wsum[1][w][m16][0]);
            sx += f.x; sy += f.y;
        }
        const float x20 = sx + fmaf(wbs0, epsB[27][0], wbl0);
        const float x21 = sy + fmaf(wbs1, epsB[27][1], wbl1);
        const float sc  = 1e-5f + 0.05f * softplus_f(Cc + x21);
        *reinterpret_cast<float2*>(&out_lds[m16 * 56 + 54]) = make_float2(x20, sc);
    }
    __syncthreads();

    // ---- coalesced output burst: 16 rows x 28 x 2 floats = 224 float4, contiguous
    if (tid < 224) {
        const float4 v = reinterpret_cast<const float4*>(out_lds)[tid];
        reinterpret_cast<float4*>(out + (size_t)b0 * 56)[tid] = v;
    }
}

extern "C" void kernel_launch(void* const* d_in, const int* in_sizes, int n_in,
                              void* d_out, int out_size, void* d_ws, size_t ws_size,
                              hipStream_t stream) {
    const float* inp    = (const float*)d_in[0];
    const float* Kw     = (const float*)d_in[1];
    const float* Rw     = (const float*)d_in[2];
    const float* bias   = (const float*)d_in[3];
    const float* dv_loc = (const float*)d_in[4];
    const float* dv_rho = (const float*)d_in[5];
    const float* dv_eps = (const float*)d_in[6];
    const float* samp   = (const float*)d_in[7];
    float* out = (float*)d_out;
    const int B = in_sizes[0] / 49;   // 8192
    dim3 grid(B / TB), block(NT);
    hipLaunchKernelGGL(fib_rnn_kernel, grid, block, 0, stream,
                       inp, Kw, Rw, bias, dv_loc, dv_rho, dv_eps, samp, out, B);
}

// Round 10
// 168.702 us; speedup vs baseline: 2.4060x; 1.3194x over previous
//
#include <hip/hip_runtime.h>
#include <math.h>

#define U 128
#define GAMMA 28
#define TB 16        // batch rows per block (one MFMA tile N-dim)
#define NT 512       // 8 waves
#define HSTR 136     // halves per hA row: 128 + 8 pad (272 B, 16B-aligned)
#define ESTR 260     // floats per wfin row: 258 -> 260 (1040 B, 16B-aligned)
#define L2E 1.4426950408889634f

typedef _Float16 half8 __attribute__((ext_vector_type(8)));
typedef _Float16 half4 __attribute__((ext_vector_type(4)));
typedef float floatx4 __attribute__((ext_vector_type(4)));

__device__ __forceinline__ float exp2_f(float x) {
#if __has_builtin(__builtin_amdgcn_exp2f)
    return __builtin_amdgcn_exp2f(x);
#else
    return exp2f(x);
#endif
}
__device__ __forceinline__ float rcp_f(float x) { return __builtin_amdgcn_rcpf(x); }
__device__ __forceinline__ float softplus_f(float x) {
    return fmaxf(x, 0.0f) + __logf(1.0f + __expf(-fabsf(x)));
}

__global__ __launch_bounds__(NT, 4) void fib_rnn_kernel(
    const float* __restrict__ inp,      // (B,49,1)
    const float* __restrict__ Kw,       // (1,384)
    const float* __restrict__ Rw,       // (128,384)
    const float* __restrict__ bias,     // (2,384)
    const float* __restrict__ dv_loc,   // (258)
    const float* __restrict__ dv_rho,   // (258)
    const float* __restrict__ dv_eps,   // (28,258)
    const float* __restrict__ samp,     // (27,B,1)
    float* __restrict__ out,            // (B,28,2)
    int B)
{
    __shared__ __align__(16) _Float16 hA[2][TB * HSTR];
    __shared__ __align__(16) float wfin[GAMMA * ESTR];   // per-step dense weights [s][2j+n]
    __shared__ float in_lds[TB * 49];
    __shared__ float samp_lds[27 * TB];
    __shared__ __align__(16) float wsum[2][8][TB][2];    // [parity][wave][row][n]
    __shared__ float epsB[GAMMA][2];
    __shared__ __align__(16) float out_lds[TB * GAMMA * 2];

    const int tid  = threadIdx.x;
    const int wv   = tid >> 6;          // wave 0..7
    const int lane = tid & 63;
    const int q    = lane >> 4;         // quad 0..3
    const int m16  = lane & 15;         // this lane's batch row
    const int j0   = wv * 16 + q * 4;   // first of this lane's 4 gate columns
    const int b0   = blockIdx.x * TB;

    const float Cc = 0.5413248546f;     // log(expm1(1))

    // ---- one-time staging
    for (int i = tid; i < TB * 48; i += NT) {
        int bl = i / 48, tt = i - bl * 48;
        in_lds[bl * 49 + tt] = inp[(size_t)(b0 + bl) * 49 + tt];
    }
    for (int i = tid; i < 2 * TB * HSTR; i += NT) (&hA[0][0])[i] = (_Float16)0.f;
    for (int i = tid; i < GAMMA * 258; i += NT) {
        int s = i / 258, t = i - 258 * s;
        float v = dv_eps[i];
        if (t < 256) {
            float sc = 1e-5f + 0.02f * softplus_f(Cc + dv_rho[t]);
            wfin[s * ESTR + t] = fmaf(sc, v, dv_loc[t]);
        } else {
            epsB[s][t - 256] = v;
        }
    }
    for (int i = tid; i < 27 * TB; i += NT) {
        int s = i >> 4, bl = i & 15;
        samp_lds[i] = samp[(size_t)s * B + b0 + bl];
    }

    // ---- stationary R^T fragments (A operand, fp16), PRE-SCALED:
    // z,r tiles by -log2e; hh tile by -2log2e — so gates use raw exp2.
    half8 Rb[3][4];
    {
        const int   tiles[3] = {wv, wv + 8, wv + 16};
        const float tsc[3]   = {-L2E, -L2E, -2.0f * L2E};
        #pragma unroll
        for (int t = 0; t < 3; ++t) {
            const int c = tiles[t] * 16 + m16;
            #pragma unroll
            for (int kt = 0; kt < 4; ++kt) {
                #pragma unroll
                for (int e = 0; e < 8; ++e)
                    Rb[t][kt][e] = (_Float16)(tsc[t] * Rw[(size_t)(kt * 32 + q * 8 + e) * 384 + c]);
            }
        }
    }

    // per-lane gate constants for columns j0..j0+3 (same scaling as Rb)
    float KzS[4], KrS[4], KhS[4], bzS[4], brS[4], bhxS[4], bhhS[4];
    #pragma unroll
    for (int i = 0; i < 4; ++i) {
        const int j = j0 + i;
        KzS[i]  = -L2E * Kw[j];
        KrS[i]  = -L2E * Kw[j + U];
        KhS[i]  = -2.0f * L2E * Kw[j + 2 * U];
        bzS[i]  = -L2E * (bias[j] + bias[384 + j]);
        brS[i]  = -L2E * (bias[j + U] + bias[384 + j + U]);
        bhxS[i] = -2.0f * L2E * bias[j + 2 * U];        // outside r-mult
        bhhS[i] = -2.0f * L2E * bias[384 + j + 2 * U];  // inside  r-mult -> acc2 init
    }
    const float wbl0 = dv_loc[256], wbl1 = dv_loc[257];
    const float wbs0 = 1e-5f + 0.02f * softplus_f(Cc + dv_rho[256]);
    const float wbs1 = 1e-5f + 0.02f * softplus_f(Cc + dv_rho[257]);

    float hprev[4] = {0.f, 0.f, 0.f, 0.f};

    __syncthreads();

    // ---- helpers
    auto mfma3 = [&](const int cu, floatx4& a0, floatx4& a1, floatx4& a2) {
        #pragma unroll
        for (int kt = 0; kt < 4; ++kt) {
            const half8 Bh = *reinterpret_cast<const half8*>(&hA[cu][m16 * HSTR + kt * 32 + q * 8]);
            a0 = __builtin_amdgcn_mfma_f32_16x16x32_f16(Rb[0][kt], Bh, a0, 0, 0, 0);
            a1 = __builtin_amdgcn_mfma_f32_16x16x32_f16(Rb[1][kt], Bh, a1, 0, 0, 0);
            a2 = __builtin_amdgcn_mfma_f32_16x16x32_f16(Rb[2][kt], Bh, a2, 0, 0, 0);
        }
    };
    // packed f32->f16 convert (v_cvt_pkrtz_f16_f32: 1 inst per 2 elems) +
    // single 8B LDS write. Builtin returns __fp16x2 -> element-cast into half4.
    auto hstore = [&](const int cu, const float hn[4]) {
        const auto lo = __builtin_amdgcn_cvt_pkrtz(hn[0], hn[1]);
        const auto hi = __builtin_amdgcn_cvt_pkrtz(hn[2], hn[3]);
        half4 hp;
        hp[0] = (_Float16)lo[0]; hp[1] = (_Float16)lo[1];
        hp[2] = (_Float16)hi[0]; hp[3] = (_Float16)hi[1];
        *reinterpret_cast<half4*>(&hA[cu ^ 1][m16 * HSTR + j0]) = hp;
    };
    // gates (R2-proven): independent exp2+rcp per gate, short chains
    auto gates4 = [&](const floatx4& az, const floatx4& ar, const floatx4& a2,
                      const float x, float hn[4]) {
        #pragma unroll
        for (int i = 0; i < 4; ++i) {
            const float z  = rcp_f(1.0f + exp2_f(az[i]));
            const float r  = rcp_f(1.0f + exp2_f(ar[i]));
            const float t  = fmaf(r, a2[i], fmaf(x, KhS[i], bhxS[i]));
            const float hh = fmaf(2.0f, rcp_f(1.0f + exp2_f(t)), -1.0f);
            hn[i] = fmaf(z, hprev[i] - hh, hh);
            hprev[i] = hn[i];
        }
    };
    auto dense_part = [&](const int s, const float hn[4]) {
        const float4 wa = *reinterpret_cast<const float4*>(&wfin[s * ESTR + 2 * j0]);
        const float4 wb = *reinterpret_cast<const float4*>(&wfin[s * ESTR + 2 * j0 + 4]);
        float pv0 = hn[0] * wa.x + hn[1] * wa.z + hn[2] * wb.x + hn[3] * wb.z;
        float pv1 = hn[0] * wa.y + hn[1] * wa.w + hn[2] * wb.y + hn[3] * wb.w;
        pv0 += __shfl_xor(pv0, 16, 64);  pv1 += __shfl_xor(pv1, 16, 64);
        pv0 += __shfl_xor(pv0, 32, 64);  pv1 += __shfl_xor(pv1, 32, 64);
        if (q == 0)
            *reinterpret_cast<float2*>(&wsum[s & 1][wv][m16][0]) = make_float2(pv0, pv1);
    };

    // ================= encoder steps 0..46 (x known ahead -> fold x@K + bias
    // into the MFMA C-init) ==================================================
    float xcur = in_lds[m16 * 49];
    #pragma unroll 2
    for (int step = 0; step < 47; ++step) {
        const int cu = step & 1;                         // constant-folds under unroll 2
        const float xnext = in_lds[m16 * 49 + step + 1]; // prefetch
        __builtin_amdgcn_s_setprio(1);                   // exchange critical-section
        floatx4 a0, a1, a2;
        #pragma unroll
        for (int i = 0; i < 4; ++i) {
            a0[i] = fmaf(xcur, KzS[i], bzS[i]);
            a1[i] = fmaf(xcur, KrS[i], brS[i]);
            a2[i] = bhhS[i];
        }
        mfma3(cu, a0, a1, a2);
        __builtin_amdgcn_s_setprio(0);                   // gates: latency-tolerant
        float hn[4];
        gates4(a0, a1, a2, xcur, hn);
        hstore(cu, hn);
        xcur = xnext;
        __syncthreads();
    }

    // ================= step 47 (last encoder step; emits dense partials s=0)
    {
        __builtin_amdgcn_s_setprio(1);
        floatx4 a0, a1, a2;
        #pragma unroll
        for (int i = 0; i < 4; ++i) {
            a0[i] = fmaf(xcur, KzS[i], bzS[i]);
            a1[i] = fmaf(xcur, KrS[i], brS[i]);
            a2[i] = bhhS[i];
        }
        mfma3(1, a0, a1, a2);
        __builtin_amdgcn_s_setprio(0);
        float hn[4];
        gates4(a0, a1, a2, xcur, hn);
        hstore(1, hn);
        dense_part(0, hn);
        __syncthreads();
    }

    // ================= feedback steps 48..74 (y from phase A; biases in C-init,
    // x*K stays as one fma per gate so phase A overlaps the MFMA chain) ======
    #pragma unroll 2
    for (int step = 48; step < 75; ++step) {
        const int cu = step & 1;
        const int sp = step - 48;
        __builtin_amdgcn_s_setprio(1);
        floatx4 a0, a1, a2;
        #pragma unroll
        for (int i = 0; i < 4; ++i) { a0[i] = bzS[i]; a1[i] = brS[i]; a2[i] = bhhS[i]; }
        mfma3(cu, a0, a1, a2);
        __builtin_amdgcn_s_setprio(0);

        // phase A: finish previous step's dense_var; produce this lane's y
        float sx = 0.f, sy = 0.f;
        #pragma unroll
        for (int w = 0; w < 8; ++w) {
            const float2 f = *reinterpret_cast<const float2*>(&wsum[sp & 1][w][m16][0]);
            sx += f.x; sy += f.y;
        }
        const float x20 = sx + fmaf(wbs0, epsB[sp][0], wbl0);
        const float x21 = sy + fmaf(wbs1, epsB[sp][1], wbl1);
        const float sc  = 1e-5f + 0.05f * softplus_f(Cc + x21);
        if (wv == 0 && q == 0)
            *reinterpret_cast<float2*>(&out_lds[m16 * 56 + sp * 2]) = make_float2(x20, sc);
        const float yv = fmaf(sc, samp_lds[sp * 16 + m16], x20);

        floatx4 az, ar;
        #pragma unroll
        for (int i = 0; i < 4; ++i) {
            az[i] = fmaf(yv, KzS[i], a0[i]);
            ar[i] = fmaf(yv, KrS[i], a1[i]);
        }
        float hn[4];
        gates4(az, ar, a2, yv, hn);
        hstore(cu, hn);
        dense_part(sp + 1, hn);
        __syncthreads();
    }

    // ---- final output s = 27 (parity 1)
    if (wv == 0 && q == 0) {
        float sx = 0.f, sy = 0.f;
        #pragma unroll
        for (int w = 0; w < 8; ++w) {
            const float2 f = *reinterpret_cast<const float2*>(&wsum[1][w][m16][0]);
            sx += f.x; sy += f.y;
        }
        const float x20 = sx + fmaf(wbs0, epsB[27][0], wbl0);
        const float x21 = sy + fmaf(wbs1, epsB[27][1], wbl1);
        const float sc  = 1e-5f + 0.05f * softplus_f(Cc + x21);
        *reinterpret_cast<float2*>(&out_lds[m16 * 56 + 54]) = make_float2(x20, sc);
    }
    __syncthreads();

    // ---- coalesced output burst: 16 rows x 28 x 2 floats = 224 float4, contiguous
    if (tid < 224) {
        const float4 v = reinterpret_cast<const float4*>(out_lds)[tid];
        reinterpret_cast<float4*>(out + (size_t)b0 * 56)[tid] = v;
    }
}

extern "C" void kernel_launch(void* const* d_in, const int* in_sizes, int n_in,
                              void* d_out, int out_size, void* d_ws, size_t ws_size,
                              hipStream_t stream) {
    const float* inp    = (const float*)d_in[0];
    const float* Kw     = (const float*)d_in[1];
    const float* Rw     = (const float*)d_in[2];
    const float* bias   = (const float*)d_in[3];
    const float* dv_loc = (const float*)d_in[4];
    const float* dv_rho = (const float*)d_in[5];
    const float* dv_eps = (const float*)d_in[6];
    const float* samp   = (const float*)d_in[7];
    float* out = (float*)d_out;
    const int B = in_sizes[0] / 49;   // 8192
    dim3 grid(B / TB), block(NT);
    hipLaunchKernelGGL(fib_rnn_kernel, grid, block, 0, stream,
                       inp, Kw, Rw, bias, dv_loc, dv_rho, dv_eps, samp, out, B);
}